// Round 2
// baseline (256.753 us; speedup 1.0000x reference)
//
#include <hip/hip_runtime.h>
#include <math.h>

// ---------------- constant tables ----------------
__constant__ int G_ORD[17] = {0,1,2,3,4,5,6, 10,11,12,13, 7,8,9, 14,15, 16};
__constant__ int G_WA[17]  = {0,2,4,6,1,3,5, 1,3,5,7, 0,4,2, 2,6, 0};
__constant__ int G_WB[17]  = {1,3,5,7,2,4,6, 0,2,4,6, 2,6,4, 0,4, 4};
__constant__ int CDESC[10][3] = {{0,0,1},{0,2,3},{0,4,5},{0,6,7},{0,1,2},{0,3,4},{0,5,6},
                                 {1,0,1},{1,2,3},{1,1,2}};
__constant__ int PDESC[6][2] = {{0,0},{0,1},{0,2},{0,3},{1,0},{1,1}};
__constant__ float2 PMAT[4][4] = {
  {{1.f,0.f},{0.f,0.f},{0.f,0.f},{1.f,0.f}},
  {{0.f,0.f},{1.f,0.f},{1.f,0.f},{0.f,0.f}},
  {{0.f,0.f},{0.f,-1.f},{0.f,1.f},{0.f,0.f}},
  {{1.f,0.f},{0.f,0.f},{0.f,0.f},{-1.f,0.f}}};

__device__ __forceinline__ float2 cmul(float2 a, float2 b){
  return make_float2(a.x*b.x - a.y*b.y, a.x*b.y + a.y*b.x);
}
__device__ __forceinline__ float2 cadd(float2 a, float2 b){
  return make_float2(a.x+b.x, a.y+b.y);
}

__device__ void u3m(float t, float p, float d, float2* u){
  float ct = cosf(0.5f*t), st = sinf(0.5f*t);
  u[0] = make_float2(ct, 0.f);
  u[1] = make_float2(-cosf(d)*st, -sinf(d)*st);
  u[2] = make_float2(cosf(p)*st,  sinf(p)*st);
  u[3] = make_float2(cosf(p+d)*ct, sinf(p+d)*ct);
}

// ---------------- kernel 0: build the 17 gate matrices, 16 lanes per gate ------
// One block x 320 threads. Gate g owns lanes [g*16, g*16+16); lane e = (r,c) entry.
// Sequential matrix chain per gate, but each 4x4 complex matmul step is 16-wide.
// Ping-pong LDS buffers, one block barrier per step. Longest chain (last gate) = 16 steps.
__global__ __launch_bounds__(320) void build_gates_kernel(
    const float* __restrict__ conv, const float* __restrict__ pool,
    const float* __restrict__ last, float2* __restrict__ G){
  __shared__ float2 gm[2][17][16];
  int t = threadIdx.x;
  int g = t >> 4, e = t & 15, r = e >> 2, c = e & 3;
  float2 A1[4], B1[4], A2[4], B2[4];
  int nsteps = 0;
  if (g < 10){
    int layer = CDESC[g][0], ra = CDESC[g][1], rb = CDESC[g][2];
    const float* cw = conv + layer*120;
    int bA = ra*15, bB = rb*15;
    u3m(cw[bA+0],  cw[bA+1],  cw[bA+2],  A1);
    u3m(cw[bB+3],  cw[bB+4],  cw[bB+5],  B1);
    u3m(cw[bA+9],  cw[bA+10], cw[bA+11], A2);
    u3m(cw[bB+12], cw[bB+13], cw[bB+14], B2);
    nsteps = 5;
  } else if (g < 16){
    nsteps = 1;
  } else if (g == 16){
    nsteps = 16;
  }
  for (int s = 0; s < 16; s++){
    if (g < 17 && s < nsteps){
      float2 T = make_float2(0.f, 0.f);
      if (g < 10){
        if (s == 0){
          // M = kron(A1,B1), entry (r,c)
          T = cmul(A1[(r>>1)*2 + (c>>1)], B1[(r&1)*2 + (c&1)]);
        } else if (s <= 3){
          // M = R_phi(P,P) * M ; s=1:ZZ(q=3), s=2:YY(q=2), s=3:XX(q=1)
          int layer = CDESC[g][0], ra = CDESC[g][1];
          float phi = conv[layer*120 + ra*15 + 5 + s];
          int q_ = 4 - s;
          float ch = cosf(0.5f*phi), sh = sinf(0.5f*phi);
          #pragma unroll
          for (int k=0;k<4;k++){
            float2 w = cmul(PMAT[q_][(r>>1)*2 + (k>>1)], PMAT[q_][(r&1)*2 + (k&1)]);
            float2 rk = make_float2(sh*w.y, -sh*w.x);
            if (k == r) rk.x += ch;
            T = cadd(T, cmul(rk, gm[s&1][g][k*4 + c]));
          }
        } else {
          // M = kron(A2,B2) * M
          #pragma unroll
          for (int k=0;k<4;k++){
            float2 k2 = cmul(A2[(r>>1)*2 + (k>>1)], B2[(r&1)*2 + (k&1)]);
            T = cadd(T, cmul(k2, gm[s&1][g][k*4 + c]));
          }
        }
      } else if (g < 16){
        int layer = PDESC[g-10][0], h = PDESC[g-10][1];
        const float* pw = pool + layer*12 + h*3;
        float2 u[4];
        u3m(pw[0], pw[1], pw[2], u);
        if (e == 0 || e == 5) T = make_float2(1.f, 0.f);
        else if (e == 10) T = u[0];
        else if (e == 11) T = u[1];
        else if (e == 14) T = u[2];
        else if (e == 15) T = u[3];
      } else {
        if (s == 0){
          T = make_float2((r==c)?1.f:0.f, 0.f);
        } else {
          int w_ = s;                 // word index 1..15
          int qa = w_ >> 2, qb = w_ & 3;
          float phi = last[s-1];
          float ch = cosf(0.5f*phi), sh = sinf(0.5f*phi);
          #pragma unroll
          for (int k=0;k<4;k++){
            float2 w = cmul(PMAT[qa][(r>>1)*2 + (k>>1)], PMAT[qb][(r&1)*2 + (k&1)]);
            float2 rk = make_float2(sh*w.y, -sh*w.x);
            if (k == r) rk.x += ch;
            T = cadd(T, cmul(rk, gm[s&1][16][k*4 + c]));
          }
        }
      }
      gm[(s+1)&1][g][e] = T;
      if (s == nsteps-1) G[g*16 + e] = T;
    }
    __syncthreads();
  }
}

// ---------------- kernel 1: apply the 17 gates to basis column ----------------
__global__ __launch_bounds__(64) void build_u_kernel(
    const float2* __restrict__ G, float2* __restrict__ U){
  __shared__ float2 gl[17][16];
  __shared__ float2 st[256];
  int t = threadIdx.x, col = blockIdx.x;
  float2* glf = (float2*)gl;
  for (int k=t; k<272; k+=64) glf[k] = G[k];
  #pragma unroll
  for (int k=t; k<256; k+=64) st[k] = make_float2(k==col ? 1.f : 0.f, 0.f);
  __syncthreads();
  for (int g=0; g<17; g++){
    int slot = G_ORD[g];
    float2 m[16];
    #pragma unroll
    for (int i=0;i<16;i++) m[i] = gl[slot][i];
    int pa = 7 - G_WA[g], pb = 7 - G_WB[g];
    int plo = pa < pb ? pa : pb, phi_ = pa < pb ? pb : pa;
    int mm = t;
    int t1   = ((mm >> plo) << (plo+1)) | (mm & ((1<<plo)-1));
    int base = ((t1 >> phi_) << (phi_+1)) | (t1 & ((1<<phi_)-1));
    int ba = 1<<pa, bb = 1<<pb;
    int i0 = base, i1 = base|bb, i2 = base|ba, i3 = base|ba|bb;
    float2 s0 = st[i0], s1 = st[i1], s2 = st[i2], s3 = st[i3];
    float2 n0 = cadd(cadd(cmul(m[0], s0), cmul(m[1], s1)), cadd(cmul(m[2], s2), cmul(m[3], s3)));
    float2 n1 = cadd(cadd(cmul(m[4], s0), cmul(m[5], s1)), cadd(cmul(m[6], s2), cmul(m[7], s3)));
    float2 n2 = cadd(cadd(cmul(m[8], s0), cmul(m[9], s1)), cadd(cmul(m[10],s2), cmul(m[11],s3)));
    float2 n3 = cadd(cadd(cmul(m[12],s0), cmul(m[13],s1)), cadd(cmul(m[14],s2), cmul(m[15],s3)));
    st[i0] = n0; st[i1] = n1; st[i2] = n2; st[i3] = n3;
    __syncthreads();
  }
  #pragma unroll
  for (int k=t; k<256; k+=64) U[k*256 + col] = st[k];
}

// ---------------- kernel 2: A[i][j] = sum_k sgn_k Re(conj(U_ki) U_kj) ----------
// 256 blocks x 1 row, 256 threads (col j). uj coalesced, ui wave-uniform broadcast.
__global__ __launch_bounds__(256) void build_a_kernel(
    const float2* __restrict__ U, float* __restrict__ A){
  int j = threadIdx.x, i = blockIdx.x;
  float a = 0.f;
  #pragma unroll 8
  for (int k=0; k<256; k++){
    float2 uj = U[k*256 + j];
    float2 ui = U[k*256 + i];
    float sgn = (k < 128) ? 1.f : -1.f;   // qubit0 = bit7 (MSB), Z eigenvalue
    a += sgn*(ui.x*uj.x + ui.y*uj.y);
  }
  A[i*256 + j] = a;
}

// ---------------- kernel 3: fused feats(tanh GEMM) + psi + q=psi^T A psi + logits
// 1024 blocks x 256 threads; 8 rows/block (wave wv owns rows r0+wv*2..+1).
// LDS = exactly 40 KB -> 4 blocks/CU with __launch_bounds__(256,4) (16 waves/CU).
// Union: red(64x68=17.4KB in As region) dies before As(32KB) staged; flds(256B)
// lives in ps head, consumed before ps rows written.
__global__ __launch_bounds__(256, 4) void main_kernel(
    const float* __restrict__ x, const float* __restrict__ fcw,
    const float* __restrict__ fcb, const float* __restrict__ Ag,
    const float* __restrict__ outw, const float* __restrict__ outb,
    float* __restrict__ out){
  __shared__ float lds[10240];        // 40960 B exact
  float* red  = lds;                  // phase F/R: 64 x 68
  float* As   = lds;                  // phase Q: 32 x 256
  float* ps   = lds + 8192;           // phase Q: 8 x 256
  float* flds = lds + 8192;           // 64 feats (8 rows x 8), dies before ps write
  int t = threadIdx.x, lane = t & 63, wv = t >> 6, jb = lane;
  int r0 = blockIdx.x * 8;
  // ---- phase F: per-wave GEMM over k=3072 (12 passes of float4), 2 rows/wave ----
  {
    int rw = r0 + wv*2;
    const float4* x4 = (const float4*)x;
    const float4* w4 = (const float4*)fcw;
    float acc[2][8];
    #pragma unroll
    for (int r=0;r<2;r++)
      #pragma unroll
      for (int o=0;o<8;o++) acc[r][o] = 0.f;
    #pragma unroll 2
    for (int p=0; p<12; p++){
      float4 wf[8];
      #pragma unroll
      for (int o=0;o<8;o++) wf[o] = w4[o*768 + p*64 + lane];
      #pragma unroll
      for (int r=0;r<2;r++){
        float4 xv = x4[(size_t)(rw+r)*768 + p*64 + lane];
        #pragma unroll
        for (int o=0;o<8;o++){
          acc[r][o] += xv.x*wf[o].x + xv.y*wf[o].y + xv.z*wf[o].z + xv.w*wf[o].w;
        }
      }
    }
    #pragma unroll
    for (int r=0;r<2;r++)
      #pragma unroll
      for (int o=0;o<8;o++)
        red[((wv*2+r)*8 + o)*68 + lane] = acc[r][o];
  }
  __syncthreads();
  // ---- phase R: LDS-transpose reduce + tanh -> flds ----
  if (t < 64){
    const float4* rp = (const float4*)(red + t*68);
    float4 s4 = make_float4(0.f,0.f,0.f,0.f);
    #pragma unroll
    for (int i=0;i<16;i++){
      float4 v = rp[i];
      s4.x += v.x; s4.y += v.y; s4.z += v.z; s4.w += v.w;
    }
    flds[t] = tanhf(s4.x + s4.y + s4.z + s4.w + fcb[t & 7]);
  }
  __syncthreads();
  // ---- phase P: build psi rows (8 rows x 256 amps; 16 threads/row, 16 amps/thr) ----
  float psi_local[16];
  if (t < 128){
    int row = t >> 4, i1 = t & 15;
    float fv[8];
    #pragma unroll
    for (int w=0; w<8; w++) fv[w] = flds[row*8 + w];
    float cc[8], ss[8];
    #pragma unroll
    for (int w=0; w<8; w++){
      float a = 0.5f*fv[w];
      __sincosf(a, &ss[w], &cc[w]);
    }
    float Hv = (i1&8 ? ss[0]:cc[0]) * (i1&4 ? ss[1]:cc[1])
             * (i1&2 ? ss[2]:cc[2]) * (i1&1 ? ss[3]:cc[3]);
    float l2[2], l4[4], l8[8], L[16];
    l2[0]=cc[4]; l2[1]=ss[4];
    #pragma unroll
    for (int a=0;a<2;a++){ l4[a*2]=l2[a]*cc[5]; l4[a*2+1]=l2[a]*ss[5]; }
    #pragma unroll
    for (int a=0;a<4;a++){ l8[a*2]=l4[a]*cc[6]; l8[a*2+1]=l4[a]*ss[6]; }
    #pragma unroll
    for (int a=0;a<8;a++){ L[a*2]=l8[a]*cc[7]; L[a*2+1]=l8[a]*ss[7]; }
    #pragma unroll
    for (int j=0;j<16;j++) psi_local[j] = Hv*L[j];
  }
  __syncthreads();   // flds reads done; safe to overwrite ps region
  if (t < 128){
    int row = t >> 4, i1 = t & 15;
    float4* dst = (float4*)(ps + row*256 + i1*16);
    #pragma unroll
    for (int qd=0; qd<4; qd++)
      dst[qd] = make_float4(psi_local[qd*4+0], psi_local[qd*4+1],
                            psi_local[qd*4+2], psi_local[qd*4+3]);
  }
  // ---- phase Q: q = psi^T A psi over 8 chunks of 32 k-rows ----
  const float4* As4 = (const float4*)As;
  const float4* ps4 = (const float4*)ps;
  const float4* Ag4 = (const float4*)Ag;
  float4 acc4[2];
  #pragma unroll
  for (int r=0;r<2;r++) acc4[r] = make_float4(0.f,0.f,0.f,0.f);
  for (int chunk=0; chunk<8; chunk++){
    __syncthreads();   // orders ps writes (first iter) / prior compute before restage
    #pragma unroll
    for (int pass=0; pass<8; pass++){
      int kk = pass*4 + wv;
      *(float4*)(As + kk*256 + jb*4) = Ag4[(chunk*32 + kk)*64 + jb];
    }
    __syncthreads();
    #pragma unroll
    for (int kq=0; kq<8; kq++){
      float4 av0 = As4[(kq*4+0)*64 + jb];
      float4 av1 = As4[(kq*4+1)*64 + jb];
      float4 av2 = As4[(kq*4+2)*64 + jb];
      float4 av3 = As4[(kq*4+3)*64 + jb];
      #pragma unroll
      for (int r=0; r<2; r++){
        float4 pv = ps4[(wv*2+r)*64 + chunk*8 + kq];   // wave-uniform broadcast
        acc4[r].x += pv.x*av0.x + pv.y*av1.x + pv.z*av2.x + pv.w*av3.x;
        acc4[r].y += pv.x*av0.y + pv.y*av1.y + pv.z*av2.y + pv.w*av3.y;
        acc4[r].z += pv.x*av0.z + pv.y*av1.z + pv.z*av2.z + pv.w*av3.z;
        acc4[r].w += pv.x*av0.w + pv.y*av1.w + pv.z*av2.w + pv.w*av3.w;
      }
    }
  }
  // ---- epilogue: q_r = psi . (A psi), butterfly over 64 lanes, 20-lane store ----
  float p[2];
  #pragma unroll
  for (int r=0; r<2; r++){
    float4 psv = ps4[(wv*2+r)*64 + jb];
    float pr = acc4[r].x*psv.x + acc4[r].y*psv.y + acc4[r].z*psv.z + acc4[r].w*psv.w;
    #pragma unroll
    for (int m=1; m<64; m<<=1) pr += __shfl_xor(pr, m, 64);
    p[r] = pr;
  }
  if (jb < 20){
    int ridx = jb / 10, c = jb - ridx*10;
    float q = (ridx==0) ? p[0] : p[1];
    out[(r0 + wv*2 + ridx)*10 + c] = q*outw[c] + outb[c];
  }
}

// ---------------- launch ----------------
extern "C" void kernel_launch(void* const* d_in, const int* in_sizes, int n_in,
                              void* d_out, int out_size, void* d_ws, size_t ws_size,
                              hipStream_t stream) {
  const float* x    = (const float*)d_in[0];
  const float* fcw  = (const float*)d_in[1];
  const float* fcb  = (const float*)d_in[2];
  const float* conv = (const float*)d_in[3];
  const float* pool = (const float*)d_in[4];
  const float* last = (const float*)d_in[5];
  const float* outw = (const float*)d_in[6];
  const float* outb = (const float*)d_in[7];
  float* out = (float*)d_out;

  float* ws = (float*)d_ws;
  float2* U  = (float2*)ws;            // 256*256 complex = 131072 floats
  float*  Am = ws + 131072;            // 65536 floats
  float2* G  = (float2*)(ws + 131072); // 544 floats, aliases Am head: G is dead
                                       // before build_a writes Am (stream-ordered)

  build_gates_kernel<<<1, 320, 0, stream>>>(conv, pool, last, G);
  build_u_kernel<<<256, 64, 0, stream>>>(G, U);
  build_a_kernel<<<256, 256, 0, stream>>>(U, Am);
  main_kernel<<<1024, 256, 0, stream>>>(x, fcw, fcb, Am, outw, outb, out);
}

// Round 3
// 248.151 us; speedup vs baseline: 1.0347x; 1.0347x over previous
//
#include <hip/hip_runtime.h>
#include <math.h>

// ---------------- constant tables ----------------
__constant__ int G_ORD[17] = {0,1,2,3,4,5,6, 10,11,12,13, 7,8,9, 14,15, 16};
__constant__ int G_WA[17]  = {0,2,4,6,1,3,5, 1,3,5,7, 0,4,2, 2,6, 0};
__constant__ int G_WB[17]  = {1,3,5,7,2,4,6, 0,2,4,6, 2,6,4, 0,4, 4};
__constant__ int CDESC[10][3] = {{0,0,1},{0,2,3},{0,4,5},{0,6,7},{0,1,2},{0,3,4},{0,5,6},
                                 {1,0,1},{1,2,3},{1,1,2}};
__constant__ int PDESC[6][2] = {{0,0},{0,1},{0,2},{0,3},{1,0},{1,1}};
__constant__ float2 PMAT[4][4] = {
  {{1.f,0.f},{0.f,0.f},{0.f,0.f},{1.f,0.f}},
  {{0.f,0.f},{1.f,0.f},{1.f,0.f},{0.f,0.f}},
  {{0.f,0.f},{0.f,-1.f},{0.f,1.f},{0.f,0.f}},
  {{1.f,0.f},{0.f,0.f},{0.f,0.f},{-1.f,0.f}}};

__device__ __forceinline__ float2 cmul(float2 a, float2 b){
  return make_float2(a.x*b.x - a.y*b.y, a.x*b.y + a.y*b.x);
}
__device__ __forceinline__ float2 cadd(float2 a, float2 b){
  return make_float2(a.x+b.x, a.y+b.y);
}

__device__ void u3m(float t, float p, float d, float2* u){
  float ct = cosf(0.5f*t), st = sinf(0.5f*t);
  u[0] = make_float2(ct, 0.f);
  u[1] = make_float2(-cosf(d)*st, -sinf(d)*st);
  u[2] = make_float2(cosf(p)*st,  sinf(p)*st);
  u[3] = make_float2(cosf(p+d)*ct, sinf(p+d)*ct);
}

// ---------------- kernel 1: build gates (16-lane-parallel, per block) + apply --
// 256 blocks x 320 threads. Phase A: gate g owned by lanes [g*16,g*16+16);
// sequential chain per gate but each 4x4 complex matmul step is 16-wide;
// ping-pong LDS, 16 barrier steps (~2 us, concurrent across blocks).
// Phase B: wave 0 applies the 17 gates to basis column blockIdx.x (unchanged math).
__global__ __launch_bounds__(320) void build_u_kernel(
    const float* __restrict__ conv, const float* __restrict__ pool,
    const float* __restrict__ last, float2* __restrict__ U){
  __shared__ float2 gm[2][17][16];
  __shared__ float2 gl[17][16];
  __shared__ float2 st[256];
  int t = threadIdx.x, col = blockIdx.x;
  // ---- phase A: build the 17 gate matrices ----
  {
    int g = t >> 4, e = t & 15, r = e >> 2, c = e & 3;
    float2 A1[4], B1[4], A2[4], B2[4];
    int nsteps = 0;
    if (g < 10){
      int layer = CDESC[g][0], ra = CDESC[g][1], rb = CDESC[g][2];
      const float* cw = conv + layer*120;
      int bA = ra*15, bB = rb*15;
      u3m(cw[bA+0],  cw[bA+1],  cw[bA+2],  A1);
      u3m(cw[bB+3],  cw[bB+4],  cw[bB+5],  B1);
      u3m(cw[bA+9],  cw[bA+10], cw[bA+11], A2);
      u3m(cw[bB+12], cw[bB+13], cw[bB+14], B2);
      nsteps = 5;
    } else if (g < 16){
      nsteps = 1;
    } else if (g == 16){
      nsteps = 16;
    }
    for (int s = 0; s < 16; s++){
      if (g < 17 && s < nsteps){
        float2 T = make_float2(0.f, 0.f);
        if (g < 10){
          if (s == 0){
            T = cmul(A1[(r>>1)*2 + (c>>1)], B1[(r&1)*2 + (c&1)]);
          } else if (s <= 3){
            int layer = CDESC[g][0], ra = CDESC[g][1];
            float phi = conv[layer*120 + ra*15 + 5 + s];
            int q_ = 4 - s;
            float ch = cosf(0.5f*phi), sh = sinf(0.5f*phi);
            #pragma unroll
            for (int k=0;k<4;k++){
              float2 w = cmul(PMAT[q_][(r>>1)*2 + (k>>1)], PMAT[q_][(r&1)*2 + (k&1)]);
              float2 rk = make_float2(sh*w.y, -sh*w.x);
              if (k == r) rk.x += ch;
              T = cadd(T, cmul(rk, gm[s&1][g][k*4 + c]));
            }
          } else {
            #pragma unroll
            for (int k=0;k<4;k++){
              float2 k2 = cmul(A2[(r>>1)*2 + (k>>1)], B2[(r&1)*2 + (k&1)]);
              T = cadd(T, cmul(k2, gm[s&1][g][k*4 + c]));
            }
          }
        } else if (g < 16){
          int layer = PDESC[g-10][0], h = PDESC[g-10][1];
          const float* pw = pool + layer*12 + h*3;
          float2 u[4];
          u3m(pw[0], pw[1], pw[2], u);
          if (e == 0 || e == 5) T = make_float2(1.f, 0.f);
          else if (e == 10) T = u[0];
          else if (e == 11) T = u[1];
          else if (e == 14) T = u[2];
          else if (e == 15) T = u[3];
        } else {
          if (s == 0){
            T = make_float2((r==c)?1.f:0.f, 0.f);
          } else {
            int w_ = s;
            int qa = w_ >> 2, qb = w_ & 3;
            float phi = last[s-1];
            float ch = cosf(0.5f*phi), sh = sinf(0.5f*phi);
            #pragma unroll
            for (int k=0;k<4;k++){
              float2 w = cmul(PMAT[qa][(r>>1)*2 + (k>>1)], PMAT[qb][(r&1)*2 + (k&1)]);
              float2 rk = make_float2(sh*w.y, -sh*w.x);
              if (k == r) rk.x += ch;
              T = cadd(T, cmul(rk, gm[s&1][16][k*4 + c]));
            }
          }
        }
        gm[(s+1)&1][g][e] = T;
        if (s == nsteps-1) gl[g][e] = T;
      }
      __syncthreads();
    }
  }
  // ---- phase B: apply gates (wave 0 only; barriers at block scope) ----
  if (t < 256) st[t] = make_float2(t==col ? 1.f : 0.f, 0.f);
  __syncthreads();
  for (int g=0; g<17; g++){
    if (t < 64){
      int slot = G_ORD[g];
      float2 m[16];
      #pragma unroll
      for (int i=0;i<16;i++) m[i] = gl[slot][i];
      int pa = 7 - G_WA[g], pb = 7 - G_WB[g];
      int plo = pa < pb ? pa : pb, phi_ = pa < pb ? pb : pa;
      int mm = t;
      int t1   = ((mm >> plo) << (plo+1)) | (mm & ((1<<plo)-1));
      int base = ((t1 >> phi_) << (phi_+1)) | (t1 & ((1<<phi_)-1));
      int ba = 1<<pa, bb = 1<<pb;
      int i0 = base, i1 = base|bb, i2 = base|ba, i3 = base|ba|bb;
      float2 s0 = st[i0], s1 = st[i1], s2 = st[i2], s3 = st[i3];
      float2 n0 = cadd(cadd(cmul(m[0], s0), cmul(m[1], s1)), cadd(cmul(m[2], s2), cmul(m[3], s3)));
      float2 n1 = cadd(cadd(cmul(m[4], s0), cmul(m[5], s1)), cadd(cmul(m[6], s2), cmul(m[7], s3)));
      float2 n2 = cadd(cadd(cmul(m[8], s0), cmul(m[9], s1)), cadd(cmul(m[10],s2), cmul(m[11],s3)));
      float2 n3 = cadd(cadd(cmul(m[12],s0), cmul(m[13],s1)), cadd(cmul(m[14],s2), cmul(m[15],s3)));
      st[i0] = n0; st[i1] = n1; st[i2] = n2; st[i3] = n3;
    }
    __syncthreads();
  }
  if (t < 256) U[t*256 + col] = st[t];
}

// ---------------- kernel 2: A[i][j] = sum_k sgn_k Re(conj(U_ki) U_kj) ----------
__global__ __launch_bounds__(256) void build_a_kernel(
    const float2* __restrict__ U, float* __restrict__ A){
  int j = threadIdx.x, i = blockIdx.x;
  float a = 0.f;
  #pragma unroll 8
  for (int k=0; k<256; k++){
    float2 uj = U[k*256 + j];
    float2 ui = U[k*256 + i];
    float sgn = (k < 128) ? 1.f : -1.f;   // qubit0 = bit7 (MSB), Z eigenvalue
    a += sgn*(ui.x*uj.x + ui.y*uj.y);
  }
  A[i*256 + j] = a;
}

// ---------------- kernel 3: fused feats(tanh GEMM) + psi + q=psi^T A psi + logits
// 1024 blocks x 256 threads; 8 rows/block.
// Phase Q is K-SPLIT: wave wv owns k-quarter [wv*64, wv*64+64) for ALL 8 rows;
// A read DIRECTLY from L2 (once per block, coalesced float4) — no LDS staging,
// no intra-Q barriers. Per-wave partial q reduced via butterfly + 32-float LDS sum.
// LDS = 26112 B (ps 8K + flds + pqred + red 17.4K, disjoint regions).
__global__ __launch_bounds__(256, 4) void main_kernel(
    const float* __restrict__ x, const float* __restrict__ fcw,
    const float* __restrict__ fcb, const float* __restrict__ Ag,
    const float* __restrict__ outw, const float* __restrict__ outb,
    float* __restrict__ out){
  __shared__ float lds[6528];
  float* ps    = lds;                 // [0,2048): 8 rows x 256 psi
  float* flds  = lds + 2048;          // [2048,2112): 64 feats
  float* pqred = lds + 2112;          // [2112,2144): 4 waves x 8 rows partial q
  float* red   = lds + 2176;          // [2176,6528): 64 x 68 GEMM partials
  int t = threadIdx.x, lane = t & 63, wv = t >> 6, jb = lane;
  int r0 = blockIdx.x * 8;
  // ---- phase F: per-wave GEMM over k=3072 (12 passes of float4), 2 rows/wave ----
  {
    int rw = r0 + wv*2;
    const float4* x4 = (const float4*)x;
    const float4* w4 = (const float4*)fcw;
    float acc[2][8];
    #pragma unroll
    for (int r=0;r<2;r++)
      #pragma unroll
      for (int o=0;o<8;o++) acc[r][o] = 0.f;
    #pragma unroll 2
    for (int p=0; p<12; p++){
      float4 wf[8];
      #pragma unroll
      for (int o=0;o<8;o++) wf[o] = w4[o*768 + p*64 + lane];
      #pragma unroll
      for (int r=0;r<2;r++){
        float4 xv = x4[(size_t)(rw+r)*768 + p*64 + lane];
        #pragma unroll
        for (int o=0;o<8;o++){
          acc[r][o] += xv.x*wf[o].x + xv.y*wf[o].y + xv.z*wf[o].z + xv.w*wf[o].w;
        }
      }
    }
    #pragma unroll
    for (int r=0;r<2;r++)
      #pragma unroll
      for (int o=0;o<8;o++)
        red[((wv*2+r)*8 + o)*68 + lane] = acc[r][o];
  }
  __syncthreads();
  // ---- phase R: LDS-transpose reduce + tanh -> flds ----
  if (t < 64){
    const float4* rp = (const float4*)(red + t*68);
    float4 s4 = make_float4(0.f,0.f,0.f,0.f);
    #pragma unroll
    for (int i=0;i<16;i++){
      float4 v = rp[i];
      s4.x += v.x; s4.y += v.y; s4.z += v.z; s4.w += v.w;
    }
    flds[t] = tanhf(s4.x + s4.y + s4.z + s4.w + fcb[t & 7]);
  }
  __syncthreads();
  // ---- phase P: build psi rows (8 rows x 256 amps; 16 threads/row) ----
  // ps is disjoint from flds/red: write directly, no staging.
  if (t < 128){
    int row = t >> 4, i1 = t & 15;
    float fv[8];
    #pragma unroll
    for (int w=0; w<8; w++) fv[w] = flds[row*8 + w];
    float cc[8], ss[8];
    #pragma unroll
    for (int w=0; w<8; w++){
      float a = 0.5f*fv[w];
      __sincosf(a, &ss[w], &cc[w]);
    }
    float Hv = (i1&8 ? ss[0]:cc[0]) * (i1&4 ? ss[1]:cc[1])
             * (i1&2 ? ss[2]:cc[2]) * (i1&1 ? ss[3]:cc[3]);
    float l2[2], l4[4], l8[8], L[16];
    l2[0]=cc[4]; l2[1]=ss[4];
    #pragma unroll
    for (int a=0;a<2;a++){ l4[a*2]=l2[a]*cc[5]; l4[a*2+1]=l2[a]*ss[5]; }
    #pragma unroll
    for (int a=0;a<4;a++){ l8[a*2]=l4[a]*cc[6]; l8[a*2+1]=l4[a]*ss[6]; }
    #pragma unroll
    for (int a=0;a<8;a++){ L[a*2]=l8[a]*cc[7]; L[a*2+1]=l8[a]*ss[7]; }
    float4* dst = (float4*)(ps + row*256 + i1*16);
    #pragma unroll
    for (int qd=0; qd<4; qd++)
      dst[qd] = make_float4(Hv*L[qd*4+0], Hv*L[qd*4+1],
                            Hv*L[qd*4+2], Hv*L[qd*4+3]);
  }
  __syncthreads();
  // ---- phase Q: k-split quadratic form. Wave wv: k in [wv*64, wv*64+64),
  // all 8 rows. A from L2 (coalesced float4), psi from LDS (wave-uniform bcast).
  const float4* ps4 = (const float4*)ps;
  const float4* Ag4 = (const float4*)Ag;
  float4 acc4[8];
  #pragma unroll
  for (int r=0;r<8;r++) acc4[r] = make_float4(0.f,0.f,0.f,0.f);
  int kbase = wv*16;   // float4-group index of this wave's k-quarter
  #pragma unroll 2
  for (int kq=0; kq<16; kq++){
    int grp = kbase + kq;
    float4 av0 = Ag4[(grp*4+0)*64 + jb];
    float4 av1 = Ag4[(grp*4+1)*64 + jb];
    float4 av2 = Ag4[(grp*4+2)*64 + jb];
    float4 av3 = Ag4[(grp*4+3)*64 + jb];
    #pragma unroll
    for (int r=0; r<8; r++){
      float4 pv = ps4[r*64 + grp];   // psi[r][4k-slice], wave-uniform broadcast
      acc4[r].x += pv.x*av0.x + pv.y*av1.x + pv.z*av2.x + pv.w*av3.x;
      acc4[r].y += pv.x*av0.y + pv.y*av1.y + pv.z*av2.y + pv.w*av3.y;
      acc4[r].z += pv.x*av0.z + pv.y*av1.z + pv.z*av2.z + pv.w*av3.z;
      acc4[r].w += pv.x*av0.w + pv.y*av1.w + pv.z*av2.w + pv.w*av3.w;
    }
  }
  // ---- epilogue: per-wave partial q_r = sum_j y^wv[r][j] psi[r][j] ----
  float p[8];
  #pragma unroll
  for (int r=0; r<8; r++){
    float4 psv = ps4[r*64 + jb];
    float pr = acc4[r].x*psv.x + acc4[r].y*psv.y + acc4[r].z*psv.z + acc4[r].w*psv.w;
    #pragma unroll
    for (int m=1; m<64; m<<=1) pr += __shfl_xor(pr, m, 64);
    p[r] = pr;
  }
  if (jb == 0){
    #pragma unroll
    for (int r=0; r<8; r++) pqred[wv*8 + r] = p[r];
  }
  __syncthreads();
  if (t < 80){
    int row = t / 10, c = t - row*10;
    float q = (pqred[row] + pqred[8 + row]) + (pqred[16 + row] + pqred[24 + row]);
    out[(r0 + row)*10 + c] = q*outw[c] + outb[c];
  }
}

// ---------------- launch ----------------
extern "C" void kernel_launch(void* const* d_in, const int* in_sizes, int n_in,
                              void* d_out, int out_size, void* d_ws, size_t ws_size,
                              hipStream_t stream) {
  const float* x    = (const float*)d_in[0];
  const float* fcw  = (const float*)d_in[1];
  const float* fcb  = (const float*)d_in[2];
  const float* conv = (const float*)d_in[3];
  const float* pool = (const float*)d_in[4];
  const float* last = (const float*)d_in[5];
  const float* outw = (const float*)d_in[6];
  const float* outb = (const float*)d_in[7];
  float* out = (float*)d_out;

  float* ws = (float*)d_ws;
  float2* U  = (float2*)ws;            // 256*256 complex = 131072 floats
  float*  Am = ws + 131072;            // 65536 floats

  build_u_kernel<<<256, 320, 0, stream>>>(conv, pool, last, U);
  build_a_kernel<<<256, 256, 0, stream>>>(U, Am);
  main_kernel<<<1024, 256, 0, stream>>>(x, fcw, fcb, Am, outw, outb, out);
}

// Round 6
// 245.293 us; speedup vs baseline: 1.0467x; 1.0117x over previous
//
#include <hip/hip_runtime.h>
#include <math.h>

// ---------------- constant tables ----------------
__constant__ int G_ORD[17] = {0,1,2,3,4,5,6, 10,11,12,13, 7,8,9, 14,15, 16};
__constant__ int G_WA[17]  = {0,2,4,6,1,3,5, 1,3,5,7, 0,4,2, 2,6, 0};
__constant__ int G_WB[17]  = {1,3,5,7,2,4,6, 0,2,4,6, 2,6,4, 0,4, 4};
__constant__ int CDESC[10][3] = {{0,0,1},{0,2,3},{0,4,5},{0,6,7},{0,1,2},{0,3,4},{0,5,6},
                                 {1,0,1},{1,2,3},{1,1,2}};
__constant__ int PDESC[6][2] = {{0,0},{0,1},{0,2},{0,3},{1,0},{1,1}};
__constant__ float2 PMAT[4][4] = {
  {{1.f,0.f},{0.f,0.f},{0.f,0.f},{1.f,0.f}},
  {{0.f,0.f},{1.f,0.f},{1.f,0.f},{0.f,0.f}},
  {{0.f,0.f},{0.f,-1.f},{0.f,1.f},{0.f,0.f}},
  {{1.f,0.f},{0.f,0.f},{0.f,0.f},{-1.f,0.f}}};

__device__ __forceinline__ float2 cmul(float2 a, float2 b){
  return make_float2(a.x*b.x - a.y*b.y, a.x*b.y + a.y*b.x);
}
__device__ __forceinline__ float2 cadd(float2 a, float2 b){
  return make_float2(a.x+b.x, a.y+b.y);
}

__device__ void u3m(float t, float p, float d, float2* u){
  float ct = cosf(0.5f*t), st = sinf(0.5f*t);
  u[0] = make_float2(ct, 0.f);
  u[1] = make_float2(-cosf(d)*st, -sinf(d)*st);
  u[2] = make_float2(cosf(p)*st,  sinf(p)*st);
  u[3] = make_float2(cosf(p+d)*ct, sinf(p+d)*ct);
}

// ---------------- kernel 1: build gates (16-lane-parallel, per block) + apply --
// 256 blocks x 320 threads. Phase A: gate g owned by lanes [g*16,g*16+16);
// 16 barrier-stepped 16-wide 4x4 complex matmuls. Phase B: wave 0 applies the
// 17 gates to basis column blockIdx.x.
__global__ __launch_bounds__(320) void build_u_kernel(
    const float* __restrict__ conv, const float* __restrict__ pool,
    const float* __restrict__ last, float2* __restrict__ U){
  __shared__ float2 gm[2][17][16];
  __shared__ float2 gl[17][16];
  __shared__ float2 st[256];
  int t = threadIdx.x, col = blockIdx.x;
  // ---- phase A: build the 17 gate matrices ----
  {
    int g = t >> 4, e = t & 15, r = e >> 2, c = e & 3;
    float2 A1[4], B1[4], A2[4], B2[4];
    int nsteps = 0;
    if (g < 10){
      int layer = CDESC[g][0], ra = CDESC[g][1], rb = CDESC[g][2];
      const float* cw = conv + layer*120;
      int bA = ra*15, bB = rb*15;
      u3m(cw[bA+0],  cw[bA+1],  cw[bA+2],  A1);
      u3m(cw[bB+3],  cw[bB+4],  cw[bB+5],  B1);
      u3m(cw[bA+9],  cw[bA+10], cw[bA+11], A2);
      u3m(cw[bB+12], cw[bB+13], cw[bB+14], B2);
      nsteps = 5;
    } else if (g < 16){
      nsteps = 1;
    } else if (g == 16){
      nsteps = 16;
    }
    for (int s = 0; s < 16; s++){
      if (g < 17 && s < nsteps){
        float2 T = make_float2(0.f, 0.f);
        if (g < 10){
          if (s == 0){
            T = cmul(A1[(r>>1)*2 + (c>>1)], B1[(r&1)*2 + (c&1)]);
          } else if (s <= 3){
            int layer = CDESC[g][0], ra = CDESC[g][1];
            float phi = conv[layer*120 + ra*15 + 5 + s];
            int q_ = 4 - s;
            float ch = cosf(0.5f*phi), sh = sinf(0.5f*phi);
            #pragma unroll
            for (int k=0;k<4;k++){
              float2 w = cmul(PMAT[q_][(r>>1)*2 + (k>>1)], PMAT[q_][(r&1)*2 + (k&1)]);
              float2 rk = make_float2(sh*w.y, -sh*w.x);
              if (k == r) rk.x += ch;
              T = cadd(T, cmul(rk, gm[s&1][g][k*4 + c]));
            }
          } else {
            #pragma unroll
            for (int k=0;k<4;k++){
              float2 k2 = cmul(A2[(r>>1)*2 + (k>>1)], B2[(r&1)*2 + (k&1)]);
              T = cadd(T, cmul(k2, gm[s&1][g][k*4 + c]));
            }
          }
        } else if (g < 16){
          int layer = PDESC[g-10][0], h = PDESC[g-10][1];
          const float* pw = pool + layer*12 + h*3;
          float2 u[4];
          u3m(pw[0], pw[1], pw[2], u);
          if (e == 0 || e == 5) T = make_float2(1.f, 0.f);
          else if (e == 10) T = u[0];
          else if (e == 11) T = u[1];
          else if (e == 14) T = u[2];
          else if (e == 15) T = u[3];
        } else {
          if (s == 0){
            T = make_float2((r==c)?1.f:0.f, 0.f);
          } else {
            int w_ = s;
            int qa = w_ >> 2, qb = w_ & 3;
            float phi = last[s-1];
            float ch = cosf(0.5f*phi), sh = sinf(0.5f*phi);
            #pragma unroll
            for (int k=0;k<4;k++){
              float2 w = cmul(PMAT[qa][(r>>1)*2 + (k>>1)], PMAT[qb][(r&1)*2 + (k&1)]);
              float2 rk = make_float2(sh*w.y, -sh*w.x);
              if (k == r) rk.x += ch;
              T = cadd(T, cmul(rk, gm[s&1][16][k*4 + c]));
            }
          }
        }
        gm[(s+1)&1][g][e] = T;
        if (s == nsteps-1) gl[g][e] = T;
      }
      __syncthreads();
    }
  }
  // ---- phase B: apply gates (wave 0 only; barriers at block scope) ----
  if (t < 256) st[t] = make_float2(t==col ? 1.f : 0.f, 0.f);
  __syncthreads();
  for (int g=0; g<17; g++){
    if (t < 64){
      int slot = G_ORD[g];
      float2 m[16];
      #pragma unroll
      for (int i=0;i<16;i++) m[i] = gl[slot][i];
      int pa = 7 - G_WA[g], pb = 7 - G_WB[g];
      int plo = pa < pb ? pa : pb, phi_ = pa < pb ? pb : pa;
      int mm = t;
      int t1   = ((mm >> plo) << (plo+1)) | (mm & ((1<<plo)-1));
      int base = ((t1 >> phi_) << (phi_+1)) | (t1 & ((1<<phi_)-1));
      int ba = 1<<pa, bb = 1<<pb;
      int i0 = base, i1 = base|bb, i2 = base|ba, i3 = base|ba|bb;
      float2 s0 = st[i0], s1 = st[i1], s2 = st[i2], s3 = st[i3];
      float2 n0 = cadd(cadd(cmul(m[0], s0), cmul(m[1], s1)), cadd(cmul(m[2], s2), cmul(m[3], s3)));
      float2 n1 = cadd(cadd(cmul(m[4], s0), cmul(m[5], s1)), cadd(cmul(m[6], s2), cmul(m[7], s3)));
      float2 n2 = cadd(cadd(cmul(m[8], s0), cmul(m[9], s1)), cadd(cmul(m[10],s2), cmul(m[11],s3)));
      float2 n3 = cadd(cadd(cmul(m[12],s0), cmul(m[13],s1)), cadd(cmul(m[14],s2), cmul(m[15],s3)));
      st[i0] = n0; st[i1] = n1; st[i2] = n2; st[i3] = n3;
    }
    __syncthreads();
  }
  if (t < 256) U[t*256 + col] = st[t];
}

// ---------------- kernel 2: A[i][j] = sum_k sgn_k Re(conj(U_ki) U_kj) ----------
__global__ __launch_bounds__(256) void build_a_kernel(
    const float2* __restrict__ U, float* __restrict__ A){
  int j = threadIdx.x, i = blockIdx.x;
  float a = 0.f;
  #pragma unroll 8
  for (int k=0; k<256; k++){
    float2 uj = U[k*256 + j];
    float2 ui = U[k*256 + i];
    float sgn = (k < 128) ? 1.f : -1.f;   // qubit0 = bit7 (MSB), Z eigenvalue
    a += sgn*(ui.x*uj.x + ui.y*uj.y);
  }
  A[i*256 + j] = a;
}

// ---------------- kernel 3: fused feats(tanh GEMM) + psi + q=psi^T A psi + logits
// 512 blocks x 256 threads; 16 rows/block (wave wv owns rows r0+wv*4..+3 in F).
// L1-miss diet: fcw staged in LDS per pass (double-buffered, reg-prefetch) kills
// the 4x per-wave fcw redundancy; 16 rows/block halves A-read bytes per CU.
// Per-CU L1-miss bytes: ~2.9 MB -> ~1.1 MB.
// LDS 51968 B, __launch_bounds__(256,2) -> 2 blocks/CU.
// Layout (floats): red [0,8704) (128x68, F/R) unions ps [0,4096) (P/Q);
// wfbuf [8704,12800) (2x512 float4); flds [12800,12928); pqred [12928,12992).
__global__ __launch_bounds__(256, 2) void main_kernel(
    const float* __restrict__ x, const float* __restrict__ fcw,
    const float* __restrict__ fcb, const float* __restrict__ Ag,
    const float* __restrict__ outw, const float* __restrict__ outb,
    float* __restrict__ out){
  __shared__ float lds[12992];
  float* red   = lds;                  // [0, 8704): 128 pairs x 68
  float* ps    = lds;                  // [0, 4096): 16 rows x 256 psi (after red dies)
  float4* wb4  = (float4*)(lds + 8704);// [8704,12800): 2 x 512 float4 fcw buffer
  float* flds  = lds + 12800;          // 128 feats (16 rows x 8)
  float* pqred = lds + 12928;          // 4 waves x 16 rows partial q
  int t = threadIdx.x, lane = t & 63, wv = t >> 6, jb = lane;
  int r0 = blockIdx.x * 16;
  // ---- phase F: per-wave GEMM over k=3072 (12 passes of float4), 4 rows/wave;
  //      fcw via LDS (staged once per pass for the whole block) ----
  {
    int rw = r0 + wv*4;
    const float4* x4 = (const float4*)x;
    const float4* w4 = (const float4*)fcw;
    float acc[4][8];
    #pragma unroll
    for (int r=0;r<4;r++)
      #pragma unroll
      for (int o=0;o<8;o++) acc[r][o] = 0.f;
    // stage pass 0
    {
      int i0 = t, i1 = t + 256;
      wb4[i0] = w4[(i0>>6)*768 + (i0&63)];
      wb4[i1] = w4[(i1>>6)*768 + (i1&63)];
    }
    __syncthreads();
    for (int p=0; p<12; p++){
      int cb = p & 1, nb = cb ^ 1;
      float4 sg0, sg1;
      if (p < 11){   // prefetch next pass's fcw tile into regs (latency under FMAs)
        int i0 = t, i1 = t + 256;
        sg0 = w4[(i0>>6)*768 + (p+1)*64 + (i0&63)];
        sg1 = w4[(i1>>6)*768 + (p+1)*64 + (i1&63)];
      }
      float4 wf[8];
      #pragma unroll
      for (int o=0;o<8;o++) wf[o] = wb4[cb*512 + o*64 + lane];
      #pragma unroll
      for (int r=0;r<4;r++){
        float4 xv = x4[(size_t)(rw+r)*768 + p*64 + lane];
        #pragma unroll
        for (int o=0;o<8;o++){
          acc[r][o] += xv.x*wf[o].x + xv.y*wf[o].y + xv.z*wf[o].z + xv.w*wf[o].w;
        }
      }
      if (p < 11){
        wb4[nb*512 + t]       = sg0;
        wb4[nb*512 + t + 256] = sg1;
      }
      __syncthreads();
    }
    #pragma unroll
    for (int r=0;r<4;r++)
      #pragma unroll
      for (int o=0;o<8;o++)
        red[((wv*4+r)*8 + o)*68 + lane] = acc[r][o];
  }
  __syncthreads();
  // ---- phase R: LDS-transpose reduce + tanh -> flds (128 = 16 rows x 8 feats) ----
  if (t < 128){
    const float4* rp = (const float4*)(red + t*68);
    float4 s4 = make_float4(0.f,0.f,0.f,0.f);
    #pragma unroll
    for (int i=0;i<16;i++){
      float4 v = rp[i];
      s4.x += v.x; s4.y += v.y; s4.z += v.z; s4.w += v.w;
    }
    flds[t] = tanhf(s4.x + s4.y + s4.z + s4.w + fcb[t & 7]);
  }
  __syncthreads();
  // ---- phase P: build psi rows (16 rows x 256 amps; 16 threads/row; red dead) ----
  {
    int row = t >> 4, i1 = t & 15;
    float fv[8];
    #pragma unroll
    for (int w=0; w<8; w++) fv[w] = flds[row*8 + w];
    float cc[8], ss[8];
    #pragma unroll
    for (int w=0; w<8; w++){
      float a = 0.5f*fv[w];
      __sincosf(a, &ss[w], &cc[w]);
    }
    float Hv = (i1&8 ? ss[0]:cc[0]) * (i1&4 ? ss[1]:cc[1])
             * (i1&2 ? ss[2]:cc[2]) * (i1&1 ? ss[3]:cc[3]);
    float l2[2], l4[4], l8[8], L[16];
    l2[0]=cc[4]; l2[1]=ss[4];
    #pragma unroll
    for (int a=0;a<2;a++){ l4[a*2]=l2[a]*cc[5]; l4[a*2+1]=l2[a]*ss[5]; }
    #pragma unroll
    for (int a=0;a<4;a++){ l8[a*2]=l4[a]*cc[6]; l8[a*2+1]=l4[a]*ss[6]; }
    #pragma unroll
    for (int a=0;a<8;a++){ L[a*2]=l8[a]*cc[7]; L[a*2+1]=l8[a]*ss[7]; }
    float4* dst = (float4*)(ps + row*256 + i1*16);
    #pragma unroll
    for (int qd=0; qd<4; qd++)
      dst[qd] = make_float4(Hv*L[qd*4+0], Hv*L[qd*4+1],
                            Hv*L[qd*4+2], Hv*L[qd*4+3]);
  }
  __syncthreads();
  // ---- phase Q: k-split quadratic form. Wave wv: k in [wv*64, wv*64+64),
  // all 16 rows. A from L2 (coalesced float4), psi from LDS (wave-uniform bcast).
  const float4* ps4 = (const float4*)ps;
  const float4* Ag4 = (const float4*)Ag;
  float4 acc4[16];
  #pragma unroll
  for (int r=0;r<16;r++) acc4[r] = make_float4(0.f,0.f,0.f,0.f);
  int kbase = wv*16;   // float4-group index of this wave's k-quarter
  #pragma unroll 2
  for (int kq=0; kq<16; kq++){
    int grp = kbase + kq;
    float4 av0 = Ag4[(grp*4+0)*64 + jb];
    float4 av1 = Ag4[(grp*4+1)*64 + jb];
    float4 av2 = Ag4[(grp*4+2)*64 + jb];
    float4 av3 = Ag4[(grp*4+3)*64 + jb];
    #pragma unroll
    for (int r=0; r<16; r++){
      float4 pv = ps4[r*64 + grp];   // psi[r][4k-slice], wave-uniform broadcast
      acc4[r].x += pv.x*av0.x + pv.y*av1.x + pv.z*av2.x + pv.w*av3.x;
      acc4[r].y += pv.x*av0.y + pv.y*av1.y + pv.z*av2.y + pv.w*av3.y;
      acc4[r].z += pv.x*av0.z + pv.y*av1.z + pv.z*av2.z + pv.w*av3.z;
      acc4[r].w += pv.x*av0.w + pv.y*av1.w + pv.z*av2.w + pv.w*av3.w;
    }
  }
  // ---- epilogue: per-wave partial q_r, butterfly, cross-wave LDS sum ----
  #pragma unroll
  for (int r=0; r<16; r++){
    float4 psv = ps4[r*64 + jb];
    float pr = acc4[r].x*psv.x + acc4[r].y*psv.y + acc4[r].z*psv.z + acc4[r].w*psv.w;
    #pragma unroll
    for (int m=1; m<64; m<<=1) pr += __shfl_xor(pr, m, 64);
    if (jb == 0) pqred[wv*16 + r] = pr;
  }
  __syncthreads();
  if (t < 160){
    int row = t / 10, c = t - row*10;
    float q = (pqred[row] + pqred[16 + row]) + (pqred[32 + row] + pqred[48 + row]);
    out[(r0 + row)*10 + c] = q*outw[c] + outb[c];
  }
}

// ---------------- launch ----------------
extern "C" void kernel_launch(void* const* d_in, const int* in_sizes, int n_in,
                              void* d_out, int out_size, void* d_ws, size_t ws_size,
                              hipStream_t stream) {
  const float* x    = (const float*)d_in[0];
  const float* fcw  = (const float*)d_in[1];
  const float* fcb  = (const float*)d_in[2];
  const float* conv = (const float*)d_in[3];
  const float* pool = (const float*)d_in[4];
  const float* last = (const float*)d_in[5];
  const float* outw = (const float*)d_in[6];
  const float* outb = (const float*)d_in[7];
  float* out = (float*)d_out;

  float* ws = (float*)d_ws;
  float2* U  = (float2*)ws;            // 256*256 complex = 131072 floats
  float*  Am = ws + 131072;            // 65536 floats

  build_u_kernel<<<256, 320, 0, stream>>>(conv, pool, last, U);
  build_a_kernel<<<256, 256, 0, stream>>>(U, Am);
  main_kernel<<<512, 256, 0, stream>>>(x, fcw, fcb, Am, outw, outb, out);
}